// Round 13
// baseline (777.228 us; speedup 1.0000x reference)
//
#include <hip/hip_runtime.h>
#include <stdint.h>
#include <math.h>

// Round 26 = R25 with stats fused into producers (all exact-integer):
// - binary convs wave-reduce their own outputs (int64 sum/sum2, order-free
//   => exact) and atomicAdd into per-layer bucketed partials; the 5 kaccum16
//   dispatches and their ~77MB of re-reads are gone.
// - kbfc accumulates FC sums via bucketed int64 atomics (f64 chain on ints
//   was exact => identical bits); k3_stats dispatches gone. ksp_fc2/k4_out2
//   finalize inline.
// - one upfront init kernel clears all partials + flags.
// All numerics-critical chains (L1 conv order, statsA/B) verbatim R25.

typedef unsigned long long u64;

#define NBK 16   // stat buckets per channel
#define SLOT 8192  // longs per Sp (512ch*16), Sp+S2p = 16384 per slot

__device__ __forceinline__ void flag_and_wave(u64* flag, u64 nz) {
    nz &= __shfl_xor(nz, 1);
    nz &= __shfl_xor(nz, 2);
    nz &= __shfl_xor(nz, 4);
    nz &= __shfl_xor(nz, 8);
    nz &= __shfl_xor(nz, 16);
    nz &= __shfl_xor(nz, 32);
    if ((threadIdx.x & 63) == 0) atomicAnd(flag, nz);
}

// wave-reduce (sv,s2v) over 64 lanes and atomically add into bucketed partials
__device__ __forceinline__ void stat_add_wave(long long* Sp, long long* S2p,
                                              int c, int bucket,
                                              long long sv, long long s2v) {
#pragma unroll
    for (int o = 1; o < 64; o <<= 1) {
        sv  += __shfl_xor(sv, o);
        s2v += __shfl_xor(s2v, o);
    }
    if ((threadIdx.x & 63) == 0) {
        atomicAdd((u64*)&Sp[c * NBK + bucket],  (u64)sv);
        atomicAdd((u64*)&S2p[c * NBK + bucket], (u64)s2v);
    }
}

__global__ void kinit(u64* __restrict__ f, long long* __restrict__ SALL, int n) {
    int i = blockIdx.x * 256 + threadIdx.x;
    if (i < n) SALL[i] = 0;
    if (blockIdx.x == 0 && threadIdx.x < 16) f[threadIdx.x] = ~0ull;
}

// ---------- L1 ----------
__global__ void kw1t(const float* __restrict__ w1, float* __restrict__ wt) {
    int i = blockIdx.x * 64 + threadIdx.x;     // 64*27
    if (i >= 64 * 27) return;
    int co = i / 27, k = i % 27;
    float v = w1[i];
    wt[k * 64 + co] = (v > 0.f) ? 1.f : ((v < 0.f) ? -1.f : 0.f);
}

// 4 pixels/thread, 2x16-channel chunks (blockIdx.y selects 32-ch half).
// Chain per output token-identical to R16..R25: (ky,kx) outer, ci inner.
__global__ __launch_bounds__(256) void k1_conv_allv2(const float* __restrict__ x,
                                                     const float* __restrict__ wt,
                                                     float* __restrict__ out) {
    int gid = blockIdx.x * 256 + threadIdx.x;  // n*256 + hw4
    int n = gid >> 8, hw0 = (gid & 255) * 4;
    int cbase = blockIdx.y * 32;
    int y = hw0 >> 5, x0 = hw0 & 31;           // 4 pixels share row y
    const float* ip = x + (size_t)n * 3 * 1024;
    for (int cc = 0; cc < 32; cc += 16) {
        int c0 = cbase + cc;
        float4 a[16];
#pragma unroll
        for (int c = 0; c < 16; ++c) a[c] = make_float4(0.f, 0.f, 0.f, 0.f);
        for (int ky = 0; ky < 3; ++ky) {
            int yy = y + ky - 1;
            bool rowok = (unsigned)yy < 32u;
            float win[3][6];
#pragma unroll
            for (int ci = 0; ci < 3; ++ci)
#pragma unroll
                for (int j = 0; j < 6; ++j) {
                    int ccx = x0 - 1 + j;
                    bool ok = rowok && ((unsigned)ccx < 32u);
                    win[ci][j] = ok ? ip[ci * 1024 + yy * 32 + ccx] : 0.f;
                }
#pragma unroll
            for (int kx = 0; kx < 3; ++kx)
#pragma unroll
                for (int ci = 0; ci < 3; ++ci) {
                    const float* wrow = wt + (ci * 9 + ky * 3 + kx) * 64 + c0;
                    float s0 = win[ci][kx], s1 = win[ci][kx + 1];
                    float s2 = win[ci][kx + 2], s3 = win[ci][kx + 3];
#pragma unroll
                    for (int c = 0; c < 16; ++c) {
                        float wv = wrow[c];
                        a[c].x = fmaf(wv, s0, a[c].x);
                        a[c].y = fmaf(wv, s1, a[c].y);
                        a[c].z = fmaf(wv, s2, a[c].z);
                        a[c].w = fmaf(wv, s3, a[c].w);
                    }
                }
        }
#pragma unroll
        for (int c = 0; c < 16; ++c)
            *(float4*)(out + ((size_t)n * 64 + c0 + c) * 1024 + hw0) = a[c];
    }
}

// stage A: per-slot partial chains, identical m-order to R16's k1_stats64.
__global__ void k1_statsA(const float* __restrict__ v, double* __restrict__ Sp,
                          double* __restrict__ S2p, int N) {
    int c = blockIdx.x;                         // 0..63
    int slot = blockIdx.y * 64 + threadIdx.x;   // 0..255
    double s = 0.0, s2 = 0.0;
    int K = N * 4;                              // chain length (m = slot + 256k)
    const float* vp = v + (size_t)c * 1024 + slot;
    int k0 = 0;
    for (; k0 + 32 <= K; k0 += 32) {
        const float* p0 = vp + (size_t)(k0 >> 2) * 65536;
        float buf[32];
#pragma unroll
        for (int j = 0; j < 32; ++j)
            buf[j] = p0[(size_t)(j >> 2) * 65536 + (j & 3) * 256];
#pragma unroll
        for (int j = 0; j < 32; ++j) {
            double t = (double)buf[j];
            s += t; s2 += t * t;
        }
    }
    for (; k0 < K; ++k0) {
        int m = slot + k0 * 256;
        double t = (double)v[((size_t)(m >> 10) * 64 + c) * 1024 + (m & 1023)];
        s += t; s2 += t * t;
    }
    Sp[c * 256 + slot] = s; S2p[c * 256 + slot] = s2;
}

// stage B: verbatim 256-slot tree + mu/r finalization.
__global__ void k1_statsB(const double* __restrict__ Sp, const double* __restrict__ S2p,
                          float* __restrict__ muF, float* __restrict__ rF, int N) {
    int c = blockIdx.x;
    __shared__ double sh[256], sh2[256];
    sh[threadIdx.x]  = Sp[c * 256 + threadIdx.x];
    sh2[threadIdx.x] = S2p[c * 256 + threadIdx.x];
    __syncthreads();
    for (int o = 128; o > 0; o >>= 1) {
        if ((int)threadIdx.x < o) { sh[threadIdx.x] += sh[threadIdx.x + o]; sh2[threadIdx.x] += sh2[threadIdx.x + o]; }
        __syncthreads();
    }
    if (threadIdx.x == 0) {
        int M = N * 1024;
        double mean = sh[0] / M;
        double var  = sh2[0] / M - mean * mean;
        if (var < 0.0) var = 0.0;
        muF[c] = (float)mean;
        rF[c]  = 1.0f / sqrtf((float)var + 1e-5f);
    }
}

// 4 pixels/thread, float4 loads along hw (channels chunked x16 for VGPRs).
__global__ void k1_signpack(const float* __restrict__ v, const float* __restrict__ muF,
                            const float* __restrict__ rF, const float* __restrict__ g,
                            const float* __restrict__ b, u64* __restrict__ B,
                            u64* __restrict__ NZ, u64* __restrict__ aflag) {
    int gid = blockIdx.x * 64 + threadIdx.x;   // n*256 + hw4
    int n = gid >> 8, hw0 = (gid & 255) * 4;
    const float* vp = v + ((size_t)n * 64) * 1024 + hw0;
    u64 bb0 = 0, bb1 = 0, bb2 = 0, bb3 = 0;
    u64 nz0 = 0, nz1 = 0, nz2 = 0, nz3 = 0;
    for (int c0 = 0; c0 < 64; c0 += 16) {
        float4 buf[16];
#pragma unroll
        for (int j = 0; j < 16; ++j)
            buf[j] = *(const float4*)(vp + (size_t)(c0 + j) * 1024);
#pragma unroll
        for (int j = 0; j < 16; ++j) {
            int c = c0 + j;
            float mc = muF[c], rc = rF[c], gc = g[c], bc = b[c];
            float d0 = buf[j].x - mc; float t0 = (d0 * rc) * gc + bc;
            float d1 = buf[j].y - mc; float t1 = (d1 * rc) * gc + bc;
            float d2 = buf[j].z - mc; float t2 = (d2 * rc) * gc + bc;
            float d3 = buf[j].w - mc; float t3 = (d3 * rc) * gc + bc;
            bb0 |= (u64)(t0 > 0.f) << c;  nz0 |= (u64)(t0 != 0.f) << c;
            bb1 |= (u64)(t1 > 0.f) << c;  nz1 |= (u64)(t1 != 0.f) << c;
            bb2 |= (u64)(t2 > 0.f) << c;  nz2 |= (u64)(t2 != 0.f) << c;
            bb3 |= (u64)(t3 > 0.f) << c;  nz3 |= (u64)(t3 != 0.f) << c;
        }
    }
    size_t o = (size_t)n * 1024 + hw0;
    B[o]     = bb0; B[o + 1]  = bb1; B[o + 2]  = bb2; B[o + 3]  = bb3;
    NZ[o]    = nz0; NZ[o + 1] = nz1; NZ[o + 2] = nz2; NZ[o + 3] = nz3;
    flag_and_wave(aflag, nz0 & nz1 & nz2 & nz3);
}

// ---------- L1 fallback path (verbatim R13/R14) ----------
__global__ void k1_conv(const float* __restrict__ x, const float* __restrict__ w1,
                        float* __restrict__ out, int grp) {
    int hw = blockIdx.x * 64 + threadIdx.x;
    int cg = blockIdx.y;
    int n  = blockIdx.z;
    int co = grp * 8 + cg;
    int y = hw >> 5, x0 = hw & 31;
    const float* ip0 = x + ((size_t)n * 3 + 0) * 1024;
    const float* ip1 = x + ((size_t)n * 3 + 1) * 1024;
    const float* ip2 = x + ((size_t)n * 3 + 2) * 1024;
    const float* wp  = w1 + (size_t)co * 27;
    float acc = 0.f;
    for (int ky = 0; ky < 3; ++ky) {
        int yy = y + ky - 1;
        if (yy < 0 || yy > 31) continue;
        for (int kx = 0; kx < 3; ++kx) {
            int xc = x0 + kx - 1;
            if (xc < 0 || xc > 31) continue;
            int sp = yy * 32 + xc;
            int wk = ky * 3 + kx;
            float w0 = wp[wk], w1v = wp[9 + wk], w2 = wp[18 + wk];
            acc += (w0  > 0.f) ? ip0[sp] : ((w0  < 0.f) ? -ip0[sp] : 0.f);
            acc += (w1v > 0.f) ? ip1[sp] : ((w1v < 0.f) ? -ip1[sp] : 0.f);
            acc += (w2  > 0.f) ? ip2[sp] : ((w2  < 0.f) ? -ip2[sp] : 0.f);
        }
    }
    out[((size_t)n * 8 + cg) * 1024 + hw] = acc;
}

__device__ __forceinline__ float ld1(const float* v, int cg, int e) {
    return v[((size_t)(e >> 10) * 8 + cg) * 1024 + (e & 1023)];
}

__global__ void k1_stats(const float* __restrict__ v, float* __restrict__ muF,
                         float* __restrict__ rF, int grp, int N) {
    int cg = blockIdx.x;
    __shared__ double sh[256], sh2[256];
    double s = 0.0, s2 = 0.0;
    int M = N * 1024;
    for (int m = threadIdx.x; m < M; m += 256) {
        double t = (double)ld1(v, cg, m);
        s += t; s2 += t * t;
    }
    sh[threadIdx.x] = s; sh2[threadIdx.x] = s2;
    __syncthreads();
    for (int o = 128; o > 0; o >>= 1) {
        if ((int)threadIdx.x < o) { sh[threadIdx.x] += sh[threadIdx.x + o]; sh2[threadIdx.x] += sh2[threadIdx.x + o]; }
        __syncthreads();
    }
    if (threadIdx.x == 0) {
        double mean = sh[0] / M;
        double var  = sh2[0] / M - mean * mean;
        if (var < 0.0) var = 0.0;
        muF[grp * 8 + cg] = (float)mean;
        rF[grp * 8 + cg]  = 1.0f / sqrtf((float)var + 1e-5f);
    }
}

__global__ void k1_sign(const float* __restrict__ v, const float* __restrict__ muF,
                        const float* __restrict__ rF, const float* __restrict__ g,
                        const float* __restrict__ b, int8_t* __restrict__ sgn, int grp) {
    int hw = blockIdx.x * 256 + threadIdx.x;
    if (hw >= 1024) return;
    int cg = blockIdx.y, n = blockIdx.z;
    int c = grp * 8 + cg;
    float d  = v[((size_t)n * 8 + cg) * 1024 + hw] - muF[c];
    float t  = (d * rF[c]) * g[c] + b[c];
    sgn[((size_t)n * 64 + c) * 1024 + hw] = (int8_t)((t > 0.f) - (t < 0.f));
}

__global__ void kpack_sgn8(const int8_t* __restrict__ s, u64* __restrict__ B,
                           u64* __restrict__ NZ, int C, int HW, u64* __restrict__ aflag) {
    int hw = blockIdx.x * 64 + threadIdx.x;
    int wd = blockIdx.y, n = blockIdx.z;
    int WRD = C >> 6;
    u64 b = 0, nz = ~0ull;
    if (hw < HW) {
        nz = 0;
        const int8_t* sp = s + ((size_t)n * C + wd * 64) * HW + hw;
        for (int j = 0; j < 64; ++j) {
            int v = sp[(size_t)j * HW];
            b  |= (u64)(v > 0) << j;
            nz |= (u64)(v != 0) << j;
        }
        size_t o = ((size_t)n * HW + hw) * WRD + wd;
        B[o] = b; NZ[o] = nz;
    }
    flag_and_wave(aflag, nz);
}

// ---------- weight packing (fused single launch) ----------
__device__ __forceinline__ void pack_wconv_body(const float* __restrict__ w,
                                                u64* __restrict__ WB, u64* __restrict__ WNZ,
                                                int Ci, int Co, u64* flag, int idx) {
    int WRD = Ci >> 6;
    u64 b = 0, nz = ~0ull;
    if (idx < Co * 9 * WRD) {
        nz = 0;
        int wd = idx % WRD, t = (idx / WRD) % 9, co = idx / (9 * WRD);
        const float* wp = w + ((size_t)co * Ci + wd * 64) * 9 + t;
        float buf[64];
#pragma unroll
        for (int j = 0; j < 64; ++j) buf[j] = wp[(size_t)j * 9];
#pragma unroll
        for (int j = 0; j < 64; ++j) {
            b  |= (u64)(buf[j] > 0.f) << j;
            nz |= (u64)(buf[j] != 0.f) << j;
        }
        WB[idx] = b; WNZ[idx] = nz;
    }
    flag_and_wave(flag, nz);
}

__device__ __forceinline__ void pack_wlinT_body(const float* __restrict__ w,
                                                u64* __restrict__ WBt, u64* __restrict__ WZt,
                                                int K, int O, u64* flag, int idx) {
    int WRD = K >> 6;
    u64 b = 0, nz = ~0ull;
    if (idx < O * WRD) {
        nz = 0;
        int wd = idx % WRD, o = idx / WRD;
        const float* wp = w + (size_t)o * K + wd * 64;
#pragma unroll 8
        for (int j = 0; j < 64; ++j) {
            float v = wp[j];
            b  |= (u64)(v > 0.f) << j;
            nz |= (u64)(v != 0.f) << j;
        }
        WBt[(size_t)wd * O + o] = b; WZt[(size_t)wd * O + o] = nz;
    }
    flag_and_wave(flag, nz);
}

__global__ void kpack_all(const float* __restrict__ w2, const float* __restrict__ w3,
                          const float* __restrict__ w4, const float* __restrict__ w5,
                          const float* __restrict__ w6, const float* __restrict__ wf1,
                          const float* __restrict__ wf2, const float* __restrict__ wf3,
                          u64* wb2B, u64* wb2Z, u64* wb3B, u64* wb3Z,
                          u64* wb4B, u64* wb4Z, u64* wb5B, u64* wb5Z,
                          u64* wb6B, u64* wb6Z, u64* wf1B, u64* wf1Z,
                          u64* wf2B, u64* wf2Z, u64* wf3B, u64* wf3Z,
                          u64* flags) {
    int b = blockIdx.x, t = threadIdx.x;
    if      (b <   3) pack_wconv_body(w2, wb2B, wb2Z,  64,  64, &flags[0], b * 256 + t);
    else if (b <   8) pack_wconv_body(w3, wb3B, wb3Z,  64, 128, &flags[1], (b - 3) * 256 + t);
    else if (b <  17) pack_wconv_body(w4, wb4B, wb4Z, 128, 128, &flags[2], (b - 8) * 256 + t);
    else if (b <  35) pack_wconv_body(w5, wb5B, wb5Z, 128, 256, &flags[3], (b - 17) * 256 + t);
    else if (b <  71) pack_wconv_body(w6, wb6B, wb6Z, 256, 256, &flags[4], (b - 35) * 256 + t);
    else if (b < 199) pack_wlinT_body(wf1, wf1B, wf1Z, 4096, 512, &flags[5], (b - 71) * 256 + t);
    else if (b < 215) pack_wlinT_body(wf2, wf2B, wf2Z,  512, 512, &flags[6], (b - 199) * 256 + t);
    else              pack_wlinT_body(wf3, wf3B, wf3Z,  512,  10, &flags[7], (b - 215) * 256 + t);
}

// ---------- binary conv cores ----------
template <int WRD, int CB>
__device__ __forceinline__ void conv_slow(const u64* __restrict__ ib, const u64* __restrict__ iz,
                                          const u64* __restrict__ wbp, const u64* __restrict__ wzp,
                                          int H, int Wi, int y, int x, int* acc) {
#pragma unroll
    for (int c = 0; c < CB; ++c) acc[c] = 0;
    for (int ky = 0; ky < 3; ++ky) {
        int yy = y + ky - 1;
        if ((unsigned)yy >= (unsigned)H) continue;
        for (int kx = 0; kx < 3; ++kx) {
            int xc = x + kx - 1;
            if ((unsigned)xc >= (unsigned)Wi) continue;
            int p = yy * Wi + xc, t = ky * 3 + kx;
            u64 xb[WRD], xz[WRD];
#pragma unroll
            for (int w = 0; w < WRD; ++w) {
                xb[w] = ib[(size_t)p * WRD + w];
                xz[w] = iz[(size_t)p * WRD + w];
            }
#pragma unroll
            for (int c = 0; c < CB; ++c) {
#pragma unroll
                for (int w = 0; w < WRD; ++w) {
                    u64 e = xz[w] & wzp[(c * 9 + t) * WRD + w];
                    acc[c] += __popcll(e) - 2 * __popcll((xb[w] ^ wbp[(c * 9 + t) * WRD + w]) & e);
                }
            }
        }
    }
}

template <int WRD, int CB>
__device__ __forceinline__ void conv_fast(const u64* __restrict__ ib,
                                          const u64* __restrict__ wbp,
                                          int H, int Wi, int y, int x, int* acc) {
    int a2[CB];
#pragma unroll
    for (int c = 0; c < CB; ++c) a2[c] = 0;
    int T = 0;
    for (int ky = 0; ky < 3; ++ky) {
        int yy = y + ky - 1;
        if ((unsigned)yy >= (unsigned)H) continue;
        for (int kx = 0; kx < 3; ++kx) {
            int xc = x + kx - 1;
            if ((unsigned)xc >= (unsigned)Wi) continue;
            int p = yy * Wi + xc, t = ky * 3 + kx;
            ++T;
            u64 xb[WRD];
#pragma unroll
            for (int w = 0; w < WRD; ++w) xb[w] = ib[(size_t)p * WRD + w];
#pragma unroll
            for (int c = 0; c < CB; ++c)
#pragma unroll
                for (int w = 0; w < WRD; ++w)
                    a2[c] += __popcll(xb[w] ^ wbp[(c * 9 + t) * WRD + w]);
        }
    }
#pragma unroll
    for (int c = 0; c < CB; ++c) acc[c] = 64 * WRD * T - 2 * a2[c];
}

template <int WRD, int CB>
__global__ void kbconv2(const u64* __restrict__ B, const u64* __restrict__ NZ,
                        const u64* __restrict__ WB, const u64* __restrict__ WNZ,
                        int16_t* __restrict__ out, int Co, int H, int Wi,
                        const u64* __restrict__ wflag, const u64* __restrict__ aflag,
                        long long* __restrict__ Sp, long long* __restrict__ S2p) {
    int hw = blockIdx.x * 64 + threadIdx.x;
    bool act = hw < H * Wi;
    int co0 = blockIdx.y * CB, n = blockIdx.z;
    int acc[CB];
#pragma unroll
    for (int c = 0; c < CB; ++c) acc[c] = 0;
    if (act) {
        int y = hw / Wi, x = hw % Wi;
        const u64* ib = B  + (size_t)n * H * Wi * WRD;
        const u64* iz = NZ + (size_t)n * H * Wi * WRD;
        const u64* wbp = WB  + (size_t)co0 * 9 * WRD;
        const u64* wzp = WNZ + (size_t)co0 * 9 * WRD;
        bool fast = ((*wflag) & (*aflag)) == ~0ull;
        if (fast) conv_fast<WRD, CB>(ib, wbp, H, Wi, y, x, acc);
        else      conv_slow<WRD, CB>(ib, iz, wbp, wzp, H, Wi, y, x, acc);
#pragma unroll
        for (int c = 0; c < CB; ++c)
            out[((size_t)n * Co + co0 + c) * H * Wi + hw] = (int16_t)acc[c];
    }
    int bucket = blockIdx.z & (NBK - 1);
#pragma unroll
    for (int c = 0; c < CB; ++c) {
        long long v = act ? acc[c] : 0;
        stat_add_wave(Sp, S2p, co0 + c, bucket, v, v * v);
    }
}

template <int WRD, int CB>
__global__ void kbconv_pool2(const u64* __restrict__ B, const u64* __restrict__ NZ,
                             const u64* __restrict__ WB, const u64* __restrict__ WNZ,
                             int16_t* __restrict__ out, int Co, int H, int Wi,
                             const u64* __restrict__ wflag, const u64* __restrict__ aflag,
                             long long* __restrict__ Sp, long long* __restrict__ S2p) {
    int Ho = H >> 1, Wo = Wi >> 1;
    int hw = blockIdx.x * 64 + threadIdx.x;
    bool act = hw < Ho * Wo;
    int co0 = blockIdx.y * CB, n = blockIdx.z;
    int best[CB];
#pragma unroll
    for (int c = 0; c < CB; ++c) best[c] = 0;
    if (act) {
        int yo = hw / Wo, xo = hw % Wo;
        const u64* ib = B  + (size_t)n * H * Wi * WRD;
        const u64* iz = NZ + (size_t)n * H * Wi * WRD;
        const u64* wbp = WB  + (size_t)co0 * 9 * WRD;
        const u64* wzp = WNZ + (size_t)co0 * 9 * WRD;
        bool fast = ((*wflag) & (*aflag)) == ~0ull;
#pragma unroll
        for (int c = 0; c < CB; ++c) best[c] = -(1 << 30);
        if (fast) {
            for (int dy = 0; dy < 2; ++dy)
                for (int dx = 0; dx < 2; ++dx) {
                    int acc[CB];
                    conv_fast<WRD, CB>(ib, wbp, H, Wi, 2 * yo + dy, 2 * xo + dx, acc);
#pragma unroll
                    for (int c = 0; c < CB; ++c) best[c] = acc[c] > best[c] ? acc[c] : best[c];
                }
        } else {
            for (int dy = 0; dy < 2; ++dy)
                for (int dx = 0; dx < 2; ++dx) {
                    int acc[CB];
                    conv_slow<WRD, CB>(ib, iz, wbp, wzp, H, Wi, 2 * yo + dy, 2 * xo + dx, acc);
#pragma unroll
                    for (int c = 0; c < CB; ++c) best[c] = acc[c] > best[c] ? acc[c] : best[c];
                }
        }
#pragma unroll
        for (int c = 0; c < CB; ++c)
            out[((size_t)n * Co + co0 + c) * Ho * Wo + hw] = (int16_t)best[c];
    }
    int bucket = blockIdx.z & (NBK - 1);
#pragma unroll
    for (int c = 0; c < CB; ++c) {
        long long v = act ? best[c] : 0;
        stat_add_wave(Sp, S2p, co0 + c, bucket, v, v * v);
    }
}

// pool variant for Ho*Wo==16: 64 lanes = 16 pixels x 4 pool positions.
template <int WRD, int CB>
__global__ void kbconv_pool2s(const u64* __restrict__ B, const u64* __restrict__ NZ,
                              const u64* __restrict__ WB, const u64* __restrict__ WNZ,
                              int16_t* __restrict__ out, int Co, int H, int Wi,
                              const u64* __restrict__ wflag, const u64* __restrict__ aflag,
                              long long* __restrict__ Sp, long long* __restrict__ S2p) {
    int Ho = H >> 1, Wo = Wi >> 1;       // Ho*Wo == 16
    int t0 = threadIdx.x;
    int pix = t0 & 15, pos = t0 >> 4;    // pos 0..3
    int co0 = blockIdx.y * CB, n = blockIdx.z;
    int yo = pix / Wo, xo = pix % Wo;
    int y = 2 * yo + (pos >> 1), x = 2 * xo + (pos & 1);
    const u64* ib = B  + (size_t)n * H * Wi * WRD;
    const u64* iz = NZ + (size_t)n * H * Wi * WRD;
    const u64* wbp = WB  + (size_t)co0 * 9 * WRD;
    const u64* wzp = WNZ + (size_t)co0 * 9 * WRD;
    bool fast = ((*wflag) & (*aflag)) == ~0ull;
    int acc[CB];
    if (fast) conv_fast<WRD, CB>(ib, wbp, H, Wi, y, x, acc);
    else      conv_slow<WRD, CB>(ib, iz, wbp, wzp, H, Wi, y, x, acc);
#pragma unroll
    for (int c = 0; c < CB; ++c) {
        int v = acc[c];
        int v1 = __shfl_xor(v, 16); v = v1 > v ? v1 : v;
        int v2 = __shfl_xor(v, 32); v = v2 > v ? v2 : v;
        acc[c] = v;
    }
    if (pos == 0) {
#pragma unroll
        for (int c = 0; c < CB; ++c)
            out[((size_t)n * Co + co0 + c) * Ho * Wo + pix] = (int16_t)acc[c];
    }
    int bucket = blockIdx.z & (NBK - 1);
#pragma unroll
    for (int c = 0; c < CB; ++c) {
        long long v = (pos == 0) ? acc[c] : 0;   // count each pooled pixel once
        stat_add_wave(Sp, S2p, co0 + c, bucket, v, v * v);
    }
}

// ---------- BN sign + pack with inline stats finalization ----------
__global__ void ksp_conv2(const int16_t* __restrict__ v,
                          const long long* __restrict__ Sp, const long long* __restrict__ S2p,
                          const float* __restrict__ g, const float* __restrict__ b,
                          u64* __restrict__ B, u64* __restrict__ NZ, int C, int HW, int N,
                          int M, u64* __restrict__ aflag) {
    __shared__ double sMu[256], sA[256], sB[256];
    for (int c = threadIdx.x; c < C; c += 64) {
        long long s = 0, s2 = 0;
        for (int i = 0; i < NBK; ++i) { s += Sp[c * NBK + i]; s2 += S2p[c * NBK + i]; }
        double mean = (double)s / M;
        double var  = (double)s2 / M - mean * mean;
        if (var < 0.0) var = 0.0;
        sMu[c] = mean;
        sA[c]  = (g ? (double)g[c] : 1.0) / sqrt(var + 1e-5);
        sB[c]  = b ? (double)b[c] : 0.0;
    }
    __syncthreads();
    int tid = blockIdx.x * 64 + threadIdx.x;
    int WRD = C >> 6;
    int HW4 = HW >> 2;
    int total = N * WRD * HW4;
    u64 nzall = ~0ull;
    if (tid < total) {
        int hw4 = tid % HW4;
        int wd  = (tid / HW4) % WRD;
        int n   = tid / (HW4 * WRD);
        const int16_t* vp = v + ((size_t)n * C + wd * 64) * HW + hw4 * 4;
        u64 b0 = 0, b1 = 0, b2 = 0, b3 = 0;
        u64 n0 = 0, n1 = 0, n2 = 0, n3 = 0;
        for (int j0 = 0; j0 < 64; j0 += 16) {
            short4 buf[16];
#pragma unroll
            for (int j = 0; j < 16; ++j)
                buf[j] = *(const short4*)(vp + (size_t)(j0 + j) * HW);
#pragma unroll
            for (int j = 0; j < 16; ++j) {
                int c = wd * 64 + j0 + j;
                double Mu = sMu[c], A = sA[c], Bb = sB[c];
                double t0 = ((double)buf[j].x - Mu) * A + Bb;
                double t1 = ((double)buf[j].y - Mu) * A + Bb;
                double t2 = ((double)buf[j].z - Mu) * A + Bb;
                double t3 = ((double)buf[j].w - Mu) * A + Bb;
                int sh = j0 + j;
                b0 |= (u64)(t0 > 0.0) << sh;  n0 |= (u64)(t0 != 0.0) << sh;
                b1 |= (u64)(t1 > 0.0) << sh;  n1 |= (u64)(t1 != 0.0) << sh;
                b2 |= (u64)(t2 > 0.0) << sh;  n2 |= (u64)(t2 != 0.0) << sh;
                b3 |= (u64)(t3 > 0.0) << sh;  n3 |= (u64)(t3 != 0.0) << sh;
            }
        }
        size_t o = ((size_t)n * HW + hw4 * 4) * WRD + wd;
        B[o] = b0;  B[o + WRD] = b1;  B[o + 2 * WRD] = b2;  B[o + 3 * WRD] = b3;
        NZ[o] = n0; NZ[o + WRD] = n1; NZ[o + 2 * WRD] = n2; NZ[o + 3 * WRD] = n3;
        nzall = n0 & n1 & n2 & n3;
    }
    flag_and_wave(aflag, nzall);
}

__global__ void ksp_flat2(const int16_t* __restrict__ v,
                          const long long* __restrict__ Sp, const long long* __restrict__ S2p,
                          const float* __restrict__ g, const float* __restrict__ b,
                          u64* __restrict__ B, u64* __restrict__ NZ, int M,
                          u64* __restrict__ aflag) {
    __shared__ double sMu[256], sA[256], sB[256];
    for (int c = threadIdx.x; c < 256; c += 64) {
        long long s = 0, s2 = 0;
        for (int i = 0; i < NBK; ++i) { s += Sp[c * NBK + i]; s2 += S2p[c * NBK + i]; }
        double mean = (double)s / M;
        double var  = (double)s2 / M - mean * mean;
        if (var < 0.0) var = 0.0;
        sMu[c] = mean;
        sA[c]  = (g ? (double)g[c] : 1.0) / sqrt(var + 1e-5);
        sB[c]  = b ? (double)b[c] : 0.0;
    }
    __syncthreads();
    int wd = threadIdx.x;
    int n  = blockIdx.x;
    const int16_t* vp = v + (size_t)n * 4096 + wd * 64;
    int16_t buf[64];
#pragma unroll
    for (int j = 0; j < 64; ++j) buf[j] = vp[j];
    u64 b2 = 0, nz = 0;
#pragma unroll
    for (int j = 0; j < 64; ++j) {
        int k = wd * 64 + j;
        int c = k >> 4;
        double t = ((double)buf[j] - sMu[c]) * sA[c] + sB[c];
        b2 |= (u64)(t > 0.0) << j;
        nz |= (u64)(t != 0.0) << j;
    }
    B[(size_t)n * 64 + wd] = b2; NZ[(size_t)n * 64 + wd] = nz;
    flag_and_wave(aflag, nz);
}

// FC sign+pack with inline finalization (exact integer partials).
__global__ void ksp_fc2(const int* __restrict__ v,
                        const long long* __restrict__ Sp, const long long* __restrict__ S2p,
                        const float* __restrict__ g, const float* __restrict__ b,
                        u64* __restrict__ B, u64* __restrict__ NZ, int C, int WRD, int N,
                        u64* __restrict__ aflag) {
    __shared__ double sMu[512], sA[512], sB[512];
    for (int c = threadIdx.x; c < C; c += 64) {
        long long s = 0, s2 = 0;
        for (int i = 0; i < NBK; ++i) { s += Sp[c * NBK + i]; s2 += S2p[c * NBK + i]; }
        double mean = (double)s / N;
        double var  = (double)s2 / N - mean * mean;
        if (var < 0.0) var = 0.0;
        sMu[c] = mean;
        sA[c]  = (g ? (double)g[c] : 1.0) / sqrt(var + 1e-5);
        sB[c]  = b ? (double)b[c] : 0.0;
    }
    __syncthreads();
    int tid = blockIdx.x * 64 + threadIdx.x;
    u64 nz = ~0ull;
    if (tid < N * WRD) {
        int n = tid / WRD, wd = tid % WRD;
        const int* vp = v + (size_t)n * C + wd * 64;
        int buf[64];
#pragma unroll
        for (int j = 0; j < 64; ++j) buf[j] = vp[j];
        u64 b2 = 0; nz = 0;
#pragma unroll
        for (int j = 0; j < 64; ++j) {
            int c = wd * 64 + j;
            double t = ((double)buf[j] - sMu[c]) * sA[c] + sB[c];
            b2 |= (u64)(t > 0.0) << j;
            nz |= (u64)(t != 0.0) << j;
        }
        B[(size_t)n * WRD + wd] = b2; NZ[(size_t)n * WRD + wd] = nz;
    }
    flag_and_wave(aflag, nz);
}

// ---------- binary FC: transposed weights + dense path + stat atomics ----------
__global__ void kbfc(const u64* __restrict__ aB, const u64* __restrict__ aNZ,
                     const u64* __restrict__ wBt, const u64* __restrict__ wZt,
                     int* __restrict__ out, int WRD, int O,
                     const u64* __restrict__ wflag, const u64* __restrict__ aflag,
                     long long* __restrict__ Sp, long long* __restrict__ S2p) {
    int o = blockIdx.x * 64 + threadIdx.x;
    if (o >= O) return;
    int n = blockIdx.y;
    const u64* ab = aB  + (size_t)n * WRD;
    const u64* az = aNZ + (size_t)n * WRD;
    bool fast = ((*wflag) & (*aflag)) == ~0ull;
    int acc;
    if (fast) {
        int a2 = 0;
        for (int w = 0; w < WRD; w += 8) {
            u64 aw[8], ww[8];
#pragma unroll
            for (int j = 0; j < 8; ++j) {
                aw[j] = ab[w + j];
                ww[j] = wBt[(size_t)(w + j) * O + o];
            }
#pragma unroll
            for (int j = 0; j < 8; ++j) a2 += __popcll(aw[j] ^ ww[j]);
        }
        acc = 64 * WRD - 2 * a2;
    } else {
        acc = 0;
        for (int w = 0; w < WRD; ++w) {
            u64 wb = wBt[(size_t)w * O + o];
            u64 wz = wZt[(size_t)w * O + o];
            u64 e = az[w] & wz;
            acc += __popcll(e) - 2 * __popcll((ab[w] ^ wb) & e);
        }
    }
    out[(size_t)n * O + o] = acc;
    int bucket = n & (NBK - 1);
    atomicAdd((u64*)&Sp[o * NBK + bucket],  (u64)(long long)acc);
    atomicAdd((u64*)&S2p[o * NBK + bucket], (u64)((long long)acc * acc));
}

// ---------- output: inline stats (exact int sums == old f64 chain) ----------
__global__ void k4_out2(const int* __restrict__ v,
                        const long long* __restrict__ Sp, const long long* __restrict__ S2p,
                        float* __restrict__ out, int N) {
    __shared__ double sMu[10], sA[10];
    if (threadIdx.x < 10) {
        int c = threadIdx.x;
        long long s = 0, s2 = 0;
        for (int i = 0; i < NBK; ++i) { s += Sp[c * NBK + i]; s2 += S2p[c * NBK + i]; }
        double mean = (double)s / N;
        double var  = (double)s2 / N - mean * mean;
        if (var < 0.0) var = 0.0;
        sMu[c] = mean;
        sA[c]  = 1.0 / sqrt(var + 1e-5);
    }
    __syncthreads();
    for (int n = threadIdx.x; n < N; n += 256) {
        double z[10];
        double mx = -1e300;
        for (int o = 0; o < 10; ++o) {
            z[o] = ((double)v[n * 10 + o] - sMu[o]) * sA[o];
            if (z[o] > mx) mx = z[o];
        }
        double s = 0.0;
        for (int o = 0; o < 10; ++o) s += exp(z[o] - mx);
        double l = mx + log(s);
        for (int o = 0; o < 10; ++o) out[n * 10 + o] = (float)(z[o] - l);
    }
}

// ---------------- host ----------------
extern "C" void kernel_launch(void* const* d_in, const int* in_sizes, int n_in,
                              void* d_out, int out_size, void* d_ws, size_t ws_size,
                              hipStream_t stream) {
    const int N = in_sizes[0] / (3 * 32 * 32);   // 512

    const float* x   = (const float*)d_in[0];
    const float* w1  = (const float*)d_in[1];
    const float* g1  = (const float*)d_in[2];
    const float* b1  = (const float*)d_in[3];
    const float* w2  = (const float*)d_in[4];
    const float* g2  = (const float*)d_in[5];
    const float* b2  = (const float*)d_in[6];
    const float* w3  = (const float*)d_in[7];
    const float* g3  = (const float*)d_in[8];
    const float* b3  = (const float*)d_in[9];
    const float* w4  = (const float*)d_in[10];
    const float* g4  = (const float*)d_in[11];
    const float* b4  = (const float*)d_in[12];
    const float* w5  = (const float*)d_in[13];
    const float* g5  = (const float*)d_in[14];
    const float* b5  = (const float*)d_in[15];
    const float* w6  = (const float*)d_in[16];
    const float* g6  = (const float*)d_in[17];
    const float* b6  = (const float*)d_in[18];
    const float* wf1 = (const float*)d_in[19];
    const float* gf1 = (const float*)d_in[20];
    const float* bf1 = (const float*)d_in[21];
    const float* wf2 = (const float*)d_in[22];
    const float* gf2 = (const float*)d_in[23];
    const float* bf2 = (const float*)d_in[24];
    const float* wf3 = (const float*)d_in[25];

    char* ws = (char*)d_ws;
    size_t off = 0;
    auto alloc = [&](size_t bytes) -> char* {
        char* p = ws + off;
        off = (off + bytes + 511) & ~(size_t)511;
        return p;
    };

    // ---- DOWN region: all post-L1 buffers at distinct offsets ----
    int16_t* t2  = (int16_t*)alloc((size_t)N * 64 * 256 * 2);
    u64* p2B = (u64*)alloc((size_t)N * 256 * 8);
    u64* p2Z = (u64*)alloc((size_t)N * 256 * 8);
    int16_t* t3  = (int16_t*)alloc((size_t)N * 128 * 256 * 2);
    u64* p3B = (u64*)alloc((size_t)N * 256 * 2 * 8);
    u64* p3Z = (u64*)alloc((size_t)N * 256 * 2 * 8);
    int16_t* t4  = (int16_t*)alloc((size_t)N * 128 * 64 * 2);
    u64* p4B = (u64*)alloc((size_t)N * 64 * 2 * 8);
    u64* p4Z = (u64*)alloc((size_t)N * 64 * 2 * 8);
    int16_t* t5  = (int16_t*)alloc((size_t)N * 256 * 64 * 2);
    u64* p5B = (u64*)alloc((size_t)N * 64 * 4 * 8);
    u64* p5Z = (u64*)alloc((size_t)N * 64 * 4 * 8);
    int16_t* t6  = (int16_t*)alloc((size_t)N * 256 * 16 * 2);
    u64* p6B = (u64*)alloc((size_t)N * 64 * 8);
    u64* p6Z = (u64*)alloc((size_t)N * 64 * 8);
    int* fc1 = (int*)alloc((size_t)N * 512 * 4);
    int* fc2 = (int*)alloc((size_t)N * 512 * 4);
    int* fc3 = (int*)alloc((size_t)N * 10 * 4);
    u64* pF1B = (u64*)alloc((size_t)N * 8 * 8);
    u64* pF1Z = (u64*)alloc((size_t)N * 8 * 8);
    u64* pF2B = (u64*)alloc((size_t)N * 8 * 8);
    u64* pF2Z = (u64*)alloc((size_t)N * 8 * 8);
    size_t down_end = off;

    // ---- L1 head overlays (dead before any DOWN buffer is written) ----
    size_t head_big = (size_t)N * 64 * 1024 * 4;      // 134.2MB f32, 64 channels
    bool big = ws_size >= head_big + ((size_t)24 << 20);
    float*  c1buf = (float*)ws;                        // big: [N][64][1024]
    float*  c1buf8 = (float*)ws;                       // fallback: [N][8][1024]
    int8_t* sgnA  = (int8_t*)(ws + (size_t)N * 8 * 1024 * 4);  // fallback only

    // ---- tail (coexists with L1 head) ----
    off = big ? (head_big > down_end ? head_big : down_end) : down_end;
    off = (off + 511) & ~(size_t)511;
    u64* p1B = (u64*)alloc((size_t)N * 1024 * 8);
    u64* p1Z = (u64*)alloc((size_t)N * 1024 * 8);
    u64* wb2B = (u64*)alloc(64  * 9 * 1 * 8);  u64* wb2Z = (u64*)alloc(64  * 9 * 1 * 8);
    u64* wb3B = (u64*)alloc(128 * 9 * 1 * 8);  u64* wb3Z = (u64*)alloc(128 * 9 * 1 * 8);
    u64* wb4B = (u64*)alloc(128 * 9 * 2 * 8);  u64* wb4Z = (u64*)alloc(128 * 9 * 2 * 8);
    u64* wb5B = (u64*)alloc(256 * 9 * 2 * 8);  u64* wb5Z = (u64*)alloc(256 * 9 * 2 * 8);
    u64* wb6B = (u64*)alloc(256 * 9 * 4 * 8);  u64* wb6Z = (u64*)alloc(256 * 9 * 4 * 8);
    u64* wf1B = (u64*)alloc(512 * 64 * 8);     u64* wf1Z = (u64*)alloc(512 * 64 * 8);
    u64* wf2B = (u64*)alloc(512 * 8 * 8);      u64* wf2Z = (u64*)alloc(512 * 8 * 8);
    u64* wf3B = (u64*)alloc(10 * 8 * 8);       u64* wf3Z = (u64*)alloc(10 * 8 * 8);
    float* wt = (float*)alloc(27 * 64 * 4);
    double* Sp  = (double*)alloc(64 * 256 * 8);
    double* S2p = (double*)alloc(64 * 256 * 8);
    // 8 stat slots (L2..L6, FC1..FC3): each SLOT Sp + SLOT S2p int64
    long long* SALL = (long long*)alloc((size_t)8 * 2 * SLOT * 8);
    u64* flags = (u64*)alloc(16 * 8);
    // [0..4]=wconv L2..L6, [5..7]=wlin FC1..FC3, [8..12]=act L1..L5,
    // [13]=act flat(L6), [14]=act FC1sign, [15]=act FC2sign
    float*  muF = (float*)alloc(64 * 4);
    float*  rF  = (float*)alloc(64 * 4);

    auto SPs  = [&](int s) { return SALL + (size_t)s * 2 * SLOT; };
    auto S2Ps = [&](int s) { return SALL + (size_t)s * 2 * SLOT + SLOT; };

    auto cdiv = [](int a, int b) { return (a + b - 1) / b; };

    // ---- init (flags + all stat partials) + fused weight pack ----
    kinit<<<cdiv(8 * 2 * SLOT, 256), 256, 0, stream>>>(flags, SALL, 8 * 2 * SLOT);
    kpack_all<<<216, 256, 0, stream>>>(w2, w3, w4, w5, w6, wf1, wf2, wf3,
                                       wb2B, wb2Z, wb3B, wb3Z, wb4B, wb4Z,
                                       wb5B, wb5Z, wb6B, wb6Z, wf1B, wf1Z,
                                       wf2B, wf2Z, wf3B, wf3Z, flags);

    // ---- L1 ----
    if (big) {
        kw1t<<<27, 64, 0, stream>>>(w1, wt);
        k1_conv_allv2<<<dim3((N * 256) / 256, 2), 256, 0, stream>>>(x, wt, c1buf);
        k1_statsA<<<dim3(64, 4), 64, 0, stream>>>(c1buf, Sp, S2p, N);
        k1_statsB<<<64, 256, 0, stream>>>(Sp, S2p, muF, rF, N);
        k1_signpack<<<(N * 256) / 64, 64, 0, stream>>>(c1buf, muF, rF, g1, b1, p1B, p1Z, &flags[8]);
    } else {
        for (int grp = 0; grp < 8; ++grp) {
            k1_conv<<<dim3(16, 8, N), 64, 0, stream>>>(x, w1, c1buf8, grp);
            k1_stats<<<8, 256, 0, stream>>>(c1buf8, muF, rF, grp, N);
            k1_sign<<<dim3(4, 8, N), 256, 0, stream>>>(c1buf8, muF, rF, g1, b1, sgnA, grp);
        }
        kpack_sgn8<<<dim3(16, 1, N), 64, 0, stream>>>(sgnA, p1B, p1Z, 64, 1024, &flags[8]);
    }

    // ---- L2: conv+pool (stats fused), sign+pack ----
    kbconv_pool2<1, 8><<<dim3(4, 8, N), 64, 0, stream>>>(p1B, p1Z, wb2B, wb2Z, t2, 64, 32, 32, &flags[0], &flags[8], SPs(0), S2Ps(0));
    ksp_conv2<<<cdiv(N * 1 * 64, 64), 64, 0, stream>>>(t2, SPs(0), S2Ps(0), g2, b2, p2B, p2Z, 64, 256, N, N * 256, &flags[9]);

    // ---- L3 ----
    kbconv2<1, 8><<<dim3(4, 16, N), 64, 0, stream>>>(p2B, p2Z, wb3B, wb3Z, t3, 128, 16, 16, &flags[1], &flags[9], SPs(1), S2Ps(1));
    ksp_conv2<<<cdiv(N * 2 * 64, 64), 64, 0, stream>>>(t3, SPs(1), S2Ps(1), g3, b3, p3B, p3Z, 128, 256, N, N * 256, &flags[10]);

    // ---- L4 ----
    kbconv_pool2<2, 8><<<dim3(1, 16, N), 64, 0, stream>>>(p3B, p3Z, wb4B, wb4Z, t4, 128, 16, 16, &flags[2], &flags[10], SPs(2), S2Ps(2));
    ksp_conv2<<<cdiv(N * 2 * 16, 64), 64, 0, stream>>>(t4, SPs(2), S2Ps(2), g4, b4, p4B, p4Z, 128, 64, N, N * 64, &flags[11]);

    // ---- L5 ----
    kbconv2<2, 8><<<dim3(1, 32, N), 64, 0, stream>>>(p4B, p4Z, wb5B, wb5Z, t5, 256, 8, 8, &flags[3], &flags[11], SPs(3), S2Ps(3));
    ksp_conv2<<<cdiv(N * 4 * 16, 64), 64, 0, stream>>>(t5, SPs(3), S2Ps(3), g5, b5, p5B, p5Z, 256, 64, N, N * 64, &flags[12]);

    // ---- L6 ----
    kbconv_pool2s<4, 8><<<dim3(1, 32, N), 64, 0, stream>>>(p5B, p5Z, wb6B, wb6Z, t6, 256, 8, 8, &flags[4], &flags[12], SPs(4), S2Ps(4));
    ksp_flat2<<<N, 64, 0, stream>>>(t6, SPs(4), S2Ps(4), g6, b6, p6B, p6Z, N * 16, &flags[13]);

    // ---- FC1 ----
    kbfc<<<dim3(8, N), 64, 0, stream>>>(p6B, p6Z, wf1B, wf1Z, fc1, 64, 512, &flags[5], &flags[13], SPs(5), S2Ps(5));
    ksp_fc2<<<cdiv(N * 8, 64), 64, 0, stream>>>(fc1, SPs(5), S2Ps(5), gf1, bf1, pF1B, pF1Z, 512, 8, N, &flags[14]);

    // ---- FC2 ----
    kbfc<<<dim3(8, N), 64, 0, stream>>>(pF1B, pF1Z, wf2B, wf2Z, fc2, 8, 512, &flags[6], &flags[14], SPs(6), S2Ps(6));
    ksp_fc2<<<cdiv(N * 8, 64), 64, 0, stream>>>(fc2, SPs(6), S2Ps(6), gf2, bf2, pF2B, pF2Z, 512, 8, N, &flags[15]);

    // ---- FC3 + bn(no affine) + log_softmax ----
    kbfc<<<dim3(1, N), 64, 0, stream>>>(pF2B, pF2Z, wf3B, wf3Z, fc3, 8, 10, &flags[7], &flags[15], SPs(7), S2Ps(7));
    k4_out2<<<1, 256, 0, stream>>>(fc3, SPs(7), S2Ps(7), (float*)d_out, N);
}

// Round 14
// 642.397 us; speedup vs baseline: 1.2099x; 1.2099x over previous
//
#include <hip/hip_runtime.h>
#include <stdint.h>
#include <math.h>

// Round 27 = revert to R24 (best measured, 642.6us). R26's producer-fused
// stats regressed: 96 extra shuffles/wave + atomic write traffic in the
// binary convs cost ~130us to save ~30us of dispatches. R24's separate
// vectorized kaccum16/kfinal2/k3_stats restored verbatim.
// Only change vs R24: kw1t folded into kpack_all (disjoint block range,
// disjoint output) — one launch saved, zero numerical impact.

typedef unsigned long long u64;

__device__ __forceinline__ void flag_and_wave(u64* flag, u64 nz) {
    nz &= __shfl_xor(nz, 1);
    nz &= __shfl_xor(nz, 2);
    nz &= __shfl_xor(nz, 4);
    nz &= __shfl_xor(nz, 8);
    nz &= __shfl_xor(nz, 16);
    nz &= __shfl_xor(nz, 32);
    if ((threadIdx.x & 63) == 0) atomicAnd(flag, nz);
}

__global__ void kflag_init(u64* __restrict__ f) {
    int i = threadIdx.x;
    if (i < 16) f[i] = ~0ull;
}

// 4 pixels/thread, 4x16-channel chunks internally, float4 stores.
// Chain per output token-identical to R16..R24: (ky,kx) outer, ci inner.
__global__ __launch_bounds__(256) void k1_conv_allv(const float* __restrict__ x,
                                                    const float* __restrict__ wt,
                                                    float* __restrict__ out) {
    int gid = blockIdx.x * 256 + threadIdx.x;  // n*256 + hw4
    int n = gid >> 8, hw0 = (gid & 255) * 4;
    int y = hw0 >> 5, x0 = hw0 & 31;           // 4 pixels share row y
    const float* ip = x + (size_t)n * 3 * 1024;
    for (int c0 = 0; c0 < 64; c0 += 16) {
        float4 a[16];
#pragma unroll
        for (int c = 0; c < 16; ++c) a[c] = make_float4(0.f, 0.f, 0.f, 0.f);
        for (int ky = 0; ky < 3; ++ky) {
            int yy = y + ky - 1;
            bool rowok = (unsigned)yy < 32u;
            float win[3][6];
#pragma unroll
            for (int ci = 0; ci < 3; ++ci)
#pragma unroll
                for (int j = 0; j < 6; ++j) {
                    int cc = x0 - 1 + j;
                    bool ok = rowok && ((unsigned)cc < 32u);
                    win[ci][j] = ok ? ip[ci * 1024 + yy * 32 + cc] : 0.f;
                }
#pragma unroll
            for (int kx = 0; kx < 3; ++kx)
#pragma unroll
                for (int ci = 0; ci < 3; ++ci) {
                    const float* wrow = wt + (ci * 9 + ky * 3 + kx) * 64 + c0;
                    float s0 = win[ci][kx], s1 = win[ci][kx + 1];
                    float s2 = win[ci][kx + 2], s3 = win[ci][kx + 3];
#pragma unroll
                    for (int c = 0; c < 16; ++c) {
                        float wv = wrow[c];
                        a[c].x = fmaf(wv, s0, a[c].x);
                        a[c].y = fmaf(wv, s1, a[c].y);
                        a[c].z = fmaf(wv, s2, a[c].z);
                        a[c].w = fmaf(wv, s3, a[c].w);
                    }
                }
        }
#pragma unroll
        for (int c = 0; c < 16; ++c)
            *(float4*)(out + ((size_t)n * 64 + c0 + c) * 1024 + hw0) = a[c];
    }
}

// stage A: per-slot partial chains, identical m-order to R16's k1_stats64.
__global__ void k1_statsA(const float* __restrict__ v, double* __restrict__ Sp,
                          double* __restrict__ S2p, int N) {
    int c = blockIdx.x;                         // 0..63
    int slot = blockIdx.y * 64 + threadIdx.x;   // 0..255
    double s = 0.0, s2 = 0.0;
    int K = N * 4;                              // chain length (m = slot + 256k)
    const float* vp = v + (size_t)c * 1024 + slot;
    int k0 = 0;
    for (; k0 + 32 <= K; k0 += 32) {
        const float* p0 = vp + (size_t)(k0 >> 2) * 65536;
        float buf[32];
#pragma unroll
        for (int j = 0; j < 32; ++j)
            buf[j] = p0[(size_t)(j >> 2) * 65536 + (j & 3) * 256];
#pragma unroll
        for (int j = 0; j < 32; ++j) {
            double t = (double)buf[j];
            s += t; s2 += t * t;
        }
    }
    for (; k0 < K; ++k0) {
        int m = slot + k0 * 256;
        double t = (double)v[((size_t)(m >> 10) * 64 + c) * 1024 + (m & 1023)];
        s += t; s2 += t * t;
    }
    Sp[c * 256 + slot] = s; S2p[c * 256 + slot] = s2;
}

// stage B: verbatim 256-slot tree + mu/r finalization.
__global__ void k1_statsB(const double* __restrict__ Sp, const double* __restrict__ S2p,
                          float* __restrict__ muF, float* __restrict__ rF, int N) {
    int c = blockIdx.x;
    __shared__ double sh[256], sh2[256];
    sh[threadIdx.x]  = Sp[c * 256 + threadIdx.x];
    sh2[threadIdx.x] = S2p[c * 256 + threadIdx.x];
    __syncthreads();
    for (int o = 128; o > 0; o >>= 1) {
        if ((int)threadIdx.x < o) { sh[threadIdx.x] += sh[threadIdx.x + o]; sh2[threadIdx.x] += sh2[threadIdx.x + o]; }
        __syncthreads();
    }
    if (threadIdx.x == 0) {
        int M = N * 1024;
        double mean = sh[0] / M;
        double var  = sh2[0] / M - mean * mean;
        if (var < 0.0) var = 0.0;
        muF[c] = (float)mean;
        rF[c]  = 1.0f / sqrtf((float)var + 1e-5f);
    }
}

// 4 pixels/thread, float4 loads along hw (channels chunked x16 for VGPRs).
__global__ void k1_signpack(const float* __restrict__ v, const float* __restrict__ muF,
                            const float* __restrict__ rF, const float* __restrict__ g,
                            const float* __restrict__ b, u64* __restrict__ B,
                            u64* __restrict__ NZ, u64* __restrict__ aflag) {
    int gid = blockIdx.x * 64 + threadIdx.x;   // n*256 + hw4
    int n = gid >> 8, hw0 = (gid & 255) * 4;
    const float* vp = v + ((size_t)n * 64) * 1024 + hw0;
    u64 bb0 = 0, bb1 = 0, bb2 = 0, bb3 = 0;
    u64 nz0 = 0, nz1 = 0, nz2 = 0, nz3 = 0;
    for (int c0 = 0; c0 < 64; c0 += 16) {
        float4 buf[16];
#pragma unroll
        for (int j = 0; j < 16; ++j)
            buf[j] = *(const float4*)(vp + (size_t)(c0 + j) * 1024);
#pragma unroll
        for (int j = 0; j < 16; ++j) {
            int c = c0 + j;
            float mc = muF[c], rc = rF[c], gc = g[c], bc = b[c];
            float d0 = buf[j].x - mc; float t0 = (d0 * rc) * gc + bc;
            float d1 = buf[j].y - mc; float t1 = (d1 * rc) * gc + bc;
            float d2 = buf[j].z - mc; float t2 = (d2 * rc) * gc + bc;
            float d3 = buf[j].w - mc; float t3 = (d3 * rc) * gc + bc;
            bb0 |= (u64)(t0 > 0.f) << c;  nz0 |= (u64)(t0 != 0.f) << c;
            bb1 |= (u64)(t1 > 0.f) << c;  nz1 |= (u64)(t1 != 0.f) << c;
            bb2 |= (u64)(t2 > 0.f) << c;  nz2 |= (u64)(t2 != 0.f) << c;
            bb3 |= (u64)(t3 > 0.f) << c;  nz3 |= (u64)(t3 != 0.f) << c;
        }
    }
    size_t o = (size_t)n * 1024 + hw0;
    B[o]     = bb0; B[o + 1]  = bb1; B[o + 2]  = bb2; B[o + 3]  = bb3;
    NZ[o]    = nz0; NZ[o + 1] = nz1; NZ[o + 2] = nz2; NZ[o + 3] = nz3;
    flag_and_wave(aflag, nz0 & nz1 & nz2 & nz3);
}

// ---------- L1 fallback path (verbatim R13/R14) ----------
__global__ void k1_conv(const float* __restrict__ x, const float* __restrict__ w1,
                        float* __restrict__ out, int grp) {
    int hw = blockIdx.x * 64 + threadIdx.x;
    int cg = blockIdx.y;
    int n  = blockIdx.z;
    int co = grp * 8 + cg;
    int y = hw >> 5, x0 = hw & 31;
    const float* ip0 = x + ((size_t)n * 3 + 0) * 1024;
    const float* ip1 = x + ((size_t)n * 3 + 1) * 1024;
    const float* ip2 = x + ((size_t)n * 3 + 2) * 1024;
    const float* wp  = w1 + (size_t)co * 27;
    float acc = 0.f;
    for (int ky = 0; ky < 3; ++ky) {
        int yy = y + ky - 1;
        if (yy < 0 || yy > 31) continue;
        for (int kx = 0; kx < 3; ++kx) {
            int xc = x0 + kx - 1;
            if (xc < 0 || xc > 31) continue;
            int sp = yy * 32 + xc;
            int wk = ky * 3 + kx;
            float w0 = wp[wk], w1v = wp[9 + wk], w2 = wp[18 + wk];
            acc += (w0  > 0.f) ? ip0[sp] : ((w0  < 0.f) ? -ip0[sp] : 0.f);
            acc += (w1v > 0.f) ? ip1[sp] : ((w1v < 0.f) ? -ip1[sp] : 0.f);
            acc += (w2  > 0.f) ? ip2[sp] : ((w2  < 0.f) ? -ip2[sp] : 0.f);
        }
    }
    out[((size_t)n * 8 + cg) * 1024 + hw] = acc;
}

__device__ __forceinline__ float ld1(const float* v, int cg, int e) {
    return v[((size_t)(e >> 10) * 8 + cg) * 1024 + (e & 1023)];
}

__global__ void k1_stats(const float* __restrict__ v, float* __restrict__ muF,
                         float* __restrict__ rF, int grp, int N) {
    int cg = blockIdx.x;
    __shared__ double sh[256], sh2[256];
    double s = 0.0, s2 = 0.0;
    int M = N * 1024;
    for (int m = threadIdx.x; m < M; m += 256) {
        double t = (double)ld1(v, cg, m);
        s += t; s2 += t * t;
    }
    sh[threadIdx.x] = s; sh2[threadIdx.x] = s2;
    __syncthreads();
    for (int o = 128; o > 0; o >>= 1) {
        if ((int)threadIdx.x < o) { sh[threadIdx.x] += sh[threadIdx.x + o]; sh2[threadIdx.x] += sh2[threadIdx.x + o]; }
        __syncthreads();
    }
    if (threadIdx.x == 0) {
        double mean = sh[0] / M;
        double var  = sh2[0] / M - mean * mean;
        if (var < 0.0) var = 0.0;
        muF[grp * 8 + cg] = (float)mean;
        rF[grp * 8 + cg]  = 1.0f / sqrtf((float)var + 1e-5f);
    }
}

__global__ void k1_sign(const float* __restrict__ v, const float* __restrict__ muF,
                        const float* __restrict__ rF, const float* __restrict__ g,
                        const float* __restrict__ b, int8_t* __restrict__ sgn, int grp) {
    int hw = blockIdx.x * 256 + threadIdx.x;
    if (hw >= 1024) return;
    int cg = blockIdx.y, n = blockIdx.z;
    int c = grp * 8 + cg;
    float d  = v[((size_t)n * 8 + cg) * 1024 + hw] - muF[c];
    float t  = (d * rF[c]) * g[c] + b[c];
    sgn[((size_t)n * 64 + c) * 1024 + hw] = (int8_t)((t > 0.f) - (t < 0.f));
}

__global__ void kpack_sgn8(const int8_t* __restrict__ s, u64* __restrict__ B,
                           u64* __restrict__ NZ, int C, int HW, u64* __restrict__ aflag) {
    int hw = blockIdx.x * 64 + threadIdx.x;
    int wd = blockIdx.y, n = blockIdx.z;
    int WRD = C >> 6;
    u64 b = 0, nz = ~0ull;
    if (hw < HW) {
        nz = 0;
        const int8_t* sp = s + ((size_t)n * C + wd * 64) * HW + hw;
        for (int j = 0; j < 64; ++j) {
            int v = sp[(size_t)j * HW];
            b  |= (u64)(v > 0) << j;
            nz |= (u64)(v != 0) << j;
        }
        size_t o = ((size_t)n * HW + hw) * WRD + wd;
        B[o] = b; NZ[o] = nz;
    }
    flag_and_wave(aflag, nz);
}

// ---------- weight packing (fused single launch, includes w1 ternary) ----------
__device__ __forceinline__ void pack_wconv_body(const float* __restrict__ w,
                                                u64* __restrict__ WB, u64* __restrict__ WNZ,
                                                int Ci, int Co, u64* flag, int idx) {
    int WRD = Ci >> 6;
    u64 b = 0, nz = ~0ull;
    if (idx < Co * 9 * WRD) {
        nz = 0;
        int wd = idx % WRD, t = (idx / WRD) % 9, co = idx / (9 * WRD);
        const float* wp = w + ((size_t)co * Ci + wd * 64) * 9 + t;
        float buf[64];
#pragma unroll
        for (int j = 0; j < 64; ++j) buf[j] = wp[(size_t)j * 9];
#pragma unroll
        for (int j = 0; j < 64; ++j) {
            b  |= (u64)(buf[j] > 0.f) << j;
            nz |= (u64)(buf[j] != 0.f) << j;
        }
        WB[idx] = b; WNZ[idx] = nz;
    }
    flag_and_wave(flag, nz);
}

__device__ __forceinline__ void pack_wlinT_body(const float* __restrict__ w,
                                                u64* __restrict__ WBt, u64* __restrict__ WZt,
                                                int K, int O, u64* flag, int idx) {
    int WRD = K >> 6;
    u64 b = 0, nz = ~0ull;
    if (idx < O * WRD) {
        nz = 0;
        int wd = idx % WRD, o = idx / WRD;
        const float* wp = w + (size_t)o * K + wd * 64;
#pragma unroll 8
        for (int j = 0; j < 64; ++j) {
            float v = wp[j];
            b  |= (u64)(v > 0.f) << j;
            nz |= (u64)(v != 0.f) << j;
        }
        WBt[(size_t)wd * O + o] = b; WZt[(size_t)wd * O + o] = nz;
    }
    flag_and_wave(flag, nz);
}

__global__ void kpack_all(const float* __restrict__ w1, const float* __restrict__ w2,
                          const float* __restrict__ w3, const float* __restrict__ w4,
                          const float* __restrict__ w5, const float* __restrict__ w6,
                          const float* __restrict__ wf1, const float* __restrict__ wf2,
                          const float* __restrict__ wf3, float* __restrict__ wt,
                          u64* wb2B, u64* wb2Z, u64* wb3B, u64* wb3Z,
                          u64* wb4B, u64* wb4Z, u64* wb5B, u64* wb5Z,
                          u64* wb6B, u64* wb6Z, u64* wf1B, u64* wf1Z,
                          u64* wf2B, u64* wf2Z, u64* wf3B, u64* wf3Z,
                          u64* flags) {
    int b = blockIdx.x, t = threadIdx.x;
    if      (b <   3) pack_wconv_body(w2, wb2B, wb2Z,  64,  64, &flags[0], b * 256 + t);
    else if (b <   8) pack_wconv_body(w3, wb3B, wb3Z,  64, 128, &flags[1], (b - 3) * 256 + t);
    else if (b <  17) pack_wconv_body(w4, wb4B, wb4Z, 128, 128, &flags[2], (b - 8) * 256 + t);
    else if (b <  35) pack_wconv_body(w5, wb5B, wb5Z, 128, 256, &flags[3], (b - 17) * 256 + t);
    else if (b <  71) pack_wconv_body(w6, wb6B, wb6Z, 256, 256, &flags[4], (b - 35) * 256 + t);
    else if (b < 199) pack_wlinT_body(wf1, wf1B, wf1Z, 4096, 512, &flags[5], (b - 71) * 256 + t);
    else if (b < 215) pack_wlinT_body(wf2, wf2B, wf2Z,  512, 512, &flags[6], (b - 199) * 256 + t);
    else if (b < 216) pack_wlinT_body(wf3, wf3B, wf3Z,  512,  10, &flags[7], (b - 215) * 256 + t);
    else {
        // w1 ternary transpose (was kw1t): i over 64*27
        int i = (b - 216) * 256 + t;
        if (i < 64 * 27) {
            int co = i / 27, k = i % 27;
            float v = w1[i];
            wt[k * 64 + co] = (v > 0.f) ? 1.f : ((v < 0.f) ? -1.f : 0.f);
        }
    }
}

// ---------- binary conv cores ----------
template <int WRD, int CB>
__device__ __forceinline__ void conv_slow(const u64* __restrict__ ib, const u64* __restrict__ iz,
                                          const u64* __restrict__ wbp, const u64* __restrict__ wzp,
                                          int H, int Wi, int y, int x, int* acc) {
#pragma unroll
    for (int c = 0; c < CB; ++c) acc[c] = 0;
    for (int ky = 0; ky < 3; ++ky) {
        int yy = y + ky - 1;
        if ((unsigned)yy >= (unsigned)H) continue;
        for (int kx = 0; kx < 3; ++kx) {
            int xc = x + kx - 1;
            if ((unsigned)xc >= (unsigned)Wi) continue;
            int p = yy * Wi + xc, t = ky * 3 + kx;
            u64 xb[WRD], xz[WRD];
#pragma unroll
            for (int w = 0; w < WRD; ++w) {
                xb[w] = ib[(size_t)p * WRD + w];
                xz[w] = iz[(size_t)p * WRD + w];
            }
#pragma unroll
            for (int c = 0; c < CB; ++c) {
#pragma unroll
                for (int w = 0; w < WRD; ++w) {
                    u64 e = xz[w] & wzp[(c * 9 + t) * WRD + w];
                    acc[c] += __popcll(e) - 2 * __popcll((xb[w] ^ wbp[(c * 9 + t) * WRD + w]) & e);
                }
            }
        }
    }
}

template <int WRD, int CB>
__device__ __forceinline__ void conv_fast(const u64* __restrict__ ib,
                                          const u64* __restrict__ wbp,
                                          int H, int Wi, int y, int x, int* acc) {
    int a2[CB];
#pragma unroll
    for (int c = 0; c < CB; ++c) a2[c] = 0;
    int T = 0;
    for (int ky = 0; ky < 3; ++ky) {
        int yy = y + ky - 1;
        if ((unsigned)yy >= (unsigned)H) continue;
        for (int kx = 0; kx < 3; ++kx) {
            int xc = x + kx - 1;
            if ((unsigned)xc >= (unsigned)Wi) continue;
            int p = yy * Wi + xc, t = ky * 3 + kx;
            ++T;
            u64 xb[WRD];
#pragma unroll
            for (int w = 0; w < WRD; ++w) xb[w] = ib[(size_t)p * WRD + w];
#pragma unroll
            for (int c = 0; c < CB; ++c)
#pragma unroll
                for (int w = 0; w < WRD; ++w)
                    a2[c] += __popcll(xb[w] ^ wbp[(c * 9 + t) * WRD + w]);
        }
    }
#pragma unroll
    for (int c = 0; c < CB; ++c) acc[c] = 64 * WRD * T - 2 * a2[c];
}

template <int WRD, int CB>
__global__ void kbconv2(const u64* __restrict__ B, const u64* __restrict__ NZ,
                        const u64* __restrict__ WB, const u64* __restrict__ WNZ,
                        int16_t* __restrict__ out, int Co, int H, int Wi,
                        const u64* __restrict__ wflag, const u64* __restrict__ aflag) {
    int hw = blockIdx.x * 64 + threadIdx.x;
    if (hw >= H * Wi) return;
    int co0 = blockIdx.y * CB, n = blockIdx.z;
    int y = hw / Wi, x = hw % Wi;
    const u64* ib = B  + (size_t)n * H * Wi * WRD;
    const u64* iz = NZ + (size_t)n * H * Wi * WRD;
    const u64* wbp = WB  + (size_t)co0 * 9 * WRD;
    const u64* wzp = WNZ + (size_t)co0 * 9 * WRD;
    bool fast = ((*wflag) & (*aflag)) == ~0ull;
    int acc[CB];
    if (fast) conv_fast<WRD, CB>(ib, wbp, H, Wi, y, x, acc);
    else      conv_slow<WRD, CB>(ib, iz, wbp, wzp, H, Wi, y, x, acc);
#pragma unroll
    for (int c = 0; c < CB; ++c)
        out[((size_t)n * Co + co0 + c) * H * Wi + hw] = (int16_t)acc[c];
}

template <int WRD, int CB>
__global__ void kbconv_pool2(const u64* __restrict__ B, const u64* __restrict__ NZ,
                             const u64* __restrict__ WB, const u64* __restrict__ WNZ,
                             int16_t* __restrict__ out, int Co, int H, int Wi,
                             const u64* __restrict__ wflag, const u64* __restrict__ aflag) {
    int Ho = H >> 1, Wo = Wi >> 1;
    int hw = blockIdx.x * 64 + threadIdx.x;
    if (hw >= Ho * Wo) return;
    int co0 = blockIdx.y * CB, n = blockIdx.z;
    int yo = hw / Wo, xo = hw % Wo;
    const u64* ib = B  + (size_t)n * H * Wi * WRD;
    const u64* iz = NZ + (size_t)n * H * Wi * WRD;
    const u64* wbp = WB  + (size_t)co0 * 9 * WRD;
    const u64* wzp = WNZ + (size_t)co0 * 9 * WRD;
    bool fast = ((*wflag) & (*aflag)) == ~0ull;
    int best[CB];
#pragma unroll
    for (int c = 0; c < CB; ++c) best[c] = -(1 << 30);
    if (fast) {
        for (int dy = 0; dy < 2; ++dy)
            for (int dx = 0; dx < 2; ++dx) {
                int acc[CB];
                conv_fast<WRD, CB>(ib, wbp, H, Wi, 2 * yo + dy, 2 * xo + dx, acc);
#pragma unroll
                for (int c = 0; c < CB; ++c) best[c] = acc[c] > best[c] ? acc[c] : best[c];
            }
    } else {
        for (int dy = 0; dy < 2; ++dy)
            for (int dx = 0; dx < 2; ++dx) {
                int acc[CB];
                conv_slow<WRD, CB>(ib, iz, wbp, wzp, H, Wi, 2 * yo + dy, 2 * xo + dx, acc);
#pragma unroll
                for (int c = 0; c < CB; ++c) best[c] = acc[c] > best[c] ? acc[c] : best[c];
            }
    }
#pragma unroll
    for (int c = 0; c < CB; ++c)
        out[((size_t)n * Co + co0 + c) * Ho * Wo + hw] = (int16_t)best[c];
}

// pool variant for Ho*Wo==16: 64 lanes = 16 pixels x 4 pool positions.
template <int WRD, int CB>
__global__ void kbconv_pool2s(const u64* __restrict__ B, const u64* __restrict__ NZ,
                              const u64* __restrict__ WB, const u64* __restrict__ WNZ,
                              int16_t* __restrict__ out, int Co, int H, int Wi,
                              const u64* __restrict__ wflag, const u64* __restrict__ aflag) {
    int Ho = H >> 1, Wo = Wi >> 1;       // Ho*Wo == 16
    int t0 = threadIdx.x;
    int pix = t0 & 15, pos = t0 >> 4;    // pos 0..3
    int co0 = blockIdx.y * CB, n = blockIdx.z;
    int yo = pix / Wo, xo = pix % Wo;
    int y = 2 * yo + (pos >> 1), x = 2 * xo + (pos & 1);
    const u64* ib = B  + (size_t)n * H * Wi * WRD;
    const u64* iz = NZ + (size_t)n * H * Wi * WRD;
    const u64* wbp = WB  + (size_t)co0 * 9 * WRD;
    const u64* wzp = WNZ + (size_t)co0 * 9 * WRD;
    bool fast = ((*wflag) & (*aflag)) == ~0ull;
    int acc[CB];
    if (fast) conv_fast<WRD, CB>(ib, wbp, H, Wi, y, x, acc);
    else      conv_slow<WRD, CB>(ib, iz, wbp, wzp, H, Wi, y, x, acc);
#pragma unroll
    for (int c = 0; c < CB; ++c) {
        int v = acc[c];
        int v1 = __shfl_xor(v, 16); v = v1 > v ? v1 : v;
        int v2 = __shfl_xor(v, 32); v = v2 > v ? v2 : v;
        acc[c] = v;
    }
    if (pos == 0) {
#pragma unroll
        for (int c = 0; c < CB; ++c)
            out[((size_t)n * Co + co0 + c) * Ho * Wo + pix] = (int16_t)acc[c];
    }
}

// ---------- conv BN stats (int64, order-free => regrouping exact) ----------
__global__ void kaccum16(const int16_t* __restrict__ v, long long* __restrict__ Sp,
                         long long* __restrict__ S2p, int C, int HW, int M) {
    int c = blockIdx.x;
    long long s = 0, s2 = 0;
    int M8 = M >> 3;
    for (int g = blockIdx.y * 256 + threadIdx.x; g < M8; g += gridDim.y * 256) {
        int m0 = g * 8;
        const int16_t* p = v + ((size_t)(m0 / HW) * C + c) * HW + (m0 % HW);
        short4 a = *(const short4*)p;
        short4 b = *(const short4*)(p + 4);
        int v0 = a.x, v1 = a.y, v2 = a.z, v3 = a.w;
        int v4 = b.x, v5 = b.y, v6 = b.z, v7 = b.w;
        s  += v0 + v1 + v2 + v3 + v4 + v5 + v6 + v7;
        s2 += (long long)v0 * v0 + (long long)v1 * v1 + (long long)v2 * v2 + (long long)v3 * v3
            + (long long)v4 * v4 + (long long)v5 * v5 + (long long)v6 * v6 + (long long)v7 * v7;
    }
    __shared__ long long sh[256], sh2[256];
    sh[threadIdx.x] = s; sh2[threadIdx.x] = s2;
    __syncthreads();
    for (int o = 128; o > 0; o >>= 1) {
        if ((int)threadIdx.x < o) { sh[threadIdx.x] += sh[threadIdx.x + o]; sh2[threadIdx.x] += sh2[threadIdx.x + o]; }
        __syncthreads();
    }
    if (threadIdx.x == 0) {
        Sp[c * gridDim.y + blockIdx.y]  = sh[0];
        S2p[c * gridDim.y + blockIdx.y] = sh2[0];
    }
}

__global__ void kfinal2(const long long* __restrict__ Sp, const long long* __restrict__ S2p,
                        int NB, const float* __restrict__ g, const float* __restrict__ b,
                        double* __restrict__ mu, double* __restrict__ Ad,
                        double* __restrict__ Bd, int C, int M) {
    int c = blockIdx.x * 64 + threadIdx.x;
    if (c >= C) return;
    long long s = 0, s2 = 0;
    for (int i = 0; i < NB; ++i) { s += Sp[c * NB + i]; s2 += S2p[c * NB + i]; }
    double mean = (double)s / M;
    double var  = (double)s2 / M - mean * mean;
    if (var < 0.0) var = 0.0;
    mu[c] = mean;
    Ad[c] = (g ? (double)g[c] : 1.0) / sqrt(var + 1e-5);
    Bd[c] = b ? (double)b[c] : 0.0;
}

// ---------- BN sign + pack: 4 pixels/thread via short4 ----------
__global__ void ksp_conv(const int16_t* __restrict__ v, const double* __restrict__ mu,
                         const double* __restrict__ Ad, const double* __restrict__ Bd,
                         u64* __restrict__ B, u64* __restrict__ NZ, int C, int HW, int N,
                         u64* __restrict__ aflag) {
    int tid = blockIdx.x * 64 + threadIdx.x;
    int WRD = C >> 6;
    int HW4 = HW >> 2;
    int total = N * WRD * HW4;
    u64 nzall = ~0ull;
    if (tid < total) {
        int hw4 = tid % HW4;
        int wd  = (tid / HW4) % WRD;
        int n   = tid / (HW4 * WRD);
        const int16_t* vp = v + ((size_t)n * C + wd * 64) * HW + hw4 * 4;
        u64 b0 = 0, b1 = 0, b2 = 0, b3 = 0;
        u64 n0 = 0, n1 = 0, n2 = 0, n3 = 0;
        for (int j0 = 0; j0 < 64; j0 += 16) {
            short4 buf[16];
#pragma unroll
            for (int j = 0; j < 16; ++j)
                buf[j] = *(const short4*)(vp + (size_t)(j0 + j) * HW);
#pragma unroll
            for (int j = 0; j < 16; ++j) {
                int c = wd * 64 + j0 + j;
                double Mu = mu[c], A = Ad[c], Bb = Bd[c];
                double t0 = ((double)buf[j].x - Mu) * A + Bb;
                double t1 = ((double)buf[j].y - Mu) * A + Bb;
                double t2 = ((double)buf[j].z - Mu) * A + Bb;
                double t3 = ((double)buf[j].w - Mu) * A + Bb;
                int sh = j0 + j;
                b0 |= (u64)(t0 > 0.0) << sh;  n0 |= (u64)(t0 != 0.0) << sh;
                b1 |= (u64)(t1 > 0.0) << sh;  n1 |= (u64)(t1 != 0.0) << sh;
                b2 |= (u64)(t2 > 0.0) << sh;  n2 |= (u64)(t2 != 0.0) << sh;
                b3 |= (u64)(t3 > 0.0) << sh;  n3 |= (u64)(t3 != 0.0) << sh;
            }
        }
        size_t o = ((size_t)n * HW + hw4 * 4) * WRD + wd;
        B[o] = b0;  B[o + WRD] = b1;  B[o + 2 * WRD] = b2;  B[o + 3 * WRD] = b3;
        NZ[o] = n0; NZ[o + WRD] = n1; NZ[o + 2 * WRD] = n2; NZ[o + 3 * WRD] = n3;
        nzall = n0 & n1 & n2 & n3;
    }
    flag_and_wave(aflag, nzall);
}

__global__ void ksp_flat(const int16_t* __restrict__ v, const double* __restrict__ mu,
                         const double* __restrict__ Ad, const double* __restrict__ Bd,
                         u64* __restrict__ B, u64* __restrict__ NZ, u64* __restrict__ aflag) {
    int wd = threadIdx.x;
    int n  = blockIdx.x;
    const int16_t* vp = v + (size_t)n * 4096 + wd * 64;
    int16_t buf[64];
#pragma unroll
    for (int j = 0; j < 64; ++j) buf[j] = vp[j];
    u64 b = 0, nz = 0;
#pragma unroll
    for (int j = 0; j < 64; ++j) {
        int k = wd * 64 + j;
        int c = k >> 4;
        double t = ((double)buf[j] - mu[c]) * Ad[c] + Bd[c];
        b  |= (u64)(t > 0.0) << j;
        nz |= (u64)(t != 0.0) << j;
    }
    B[(size_t)n * 64 + wd] = b; NZ[(size_t)n * 64 + wd] = nz;
    flag_and_wave(aflag, nz);
}

__global__ void ksp_fc(const int* __restrict__ v, const double* __restrict__ mu,
                       const double* __restrict__ Ad, const double* __restrict__ Bd,
                       u64* __restrict__ B, u64* __restrict__ NZ, int C, int WRD, int N,
                       u64* __restrict__ aflag) {
    int tid = blockIdx.x * 64 + threadIdx.x;
    u64 nz = ~0ull;
    if (tid < N * WRD) {
        int n = tid / WRD, wd = tid % WRD;
        const int* vp = v + (size_t)n * C + wd * 64;
        int buf[64];
#pragma unroll
        for (int j = 0; j < 64; ++j) buf[j] = vp[j];
        u64 b = 0; nz = 0;
#pragma unroll
        for (int j = 0; j < 64; ++j) {
            int c = wd * 64 + j;
            double t = ((double)buf[j] - mu[c]) * Ad[c] + Bd[c];
            b  |= (u64)(t > 0.0) << j;
            nz |= (u64)(t != 0.0) << j;
        }
        B[(size_t)n * WRD + wd] = b; NZ[(size_t)n * WRD + wd] = nz;
    }
    flag_and_wave(aflag, nz);
}

// ---------- binary FC: transposed coalesced weights + dense fast path ----------
__global__ void kbfc(const u64* __restrict__ aB, const u64* __restrict__ aNZ,
                     const u64* __restrict__ wBt, const u64* __restrict__ wZt,
                     int* __restrict__ out, int WRD, int O,
                     const u64* __restrict__ wflag, const u64* __restrict__ aflag) {
    int o = blockIdx.x * 64 + threadIdx.x;
    if (o >= O) return;
    int n = blockIdx.y;
    const u64* ab = aB  + (size_t)n * WRD;
    const u64* az = aNZ + (size_t)n * WRD;
    bool fast = ((*wflag) & (*aflag)) == ~0ull;
    int acc;
    if (fast) {
        int a2 = 0;
        for (int w = 0; w < WRD; w += 8) {
            u64 aw[8], ww[8];
#pragma unroll
            for (int j = 0; j < 8; ++j) {
                aw[j] = ab[w + j];
                ww[j] = wBt[(size_t)(w + j) * O + o];
            }
#pragma unroll
            for (int j = 0; j < 8; ++j) a2 += __popcll(aw[j] ^ ww[j]);
        }
        acc = 64 * WRD - 2 * a2;
    } else {
        acc = 0;
        for (int w = 0; w < WRD; ++w) {
            u64 wb = wBt[(size_t)w * O + o];
            u64 wz = wZt[(size_t)w * O + o];
            u64 e = az[w] & wz;
            acc += __popcll(e) - 2 * __popcll((ab[w] ^ wb) & e);
        }
    }
    out[(size_t)n * O + o] = acc;
}

// ---------- FC stats / output ----------
__global__ void k3_stats(const int* __restrict__ v, int N, int C,
                         const float* __restrict__ g, const float* __restrict__ b,
                         double* __restrict__ mu, double* __restrict__ Ad,
                         double* __restrict__ Bd) {
    int c = blockIdx.x;
    __shared__ double sh[256], sh2[256];
    double s = 0.0, s2 = 0.0;
    for (int n = threadIdx.x; n < N; n += 256) {
        double t = (double)v[(size_t)n * C + c];
        s += t; s2 += t * t;
    }
    sh[threadIdx.x] = s; sh2[threadIdx.x] = s2;
    __syncthreads();
    for (int o = 128; o > 0; o >>= 1) {
        if ((int)threadIdx.x < o) { sh[threadIdx.x] += sh[threadIdx.x + o]; sh2[threadIdx.x] += sh2[threadIdx.x + o]; }
        __syncthreads();
    }
    if (threadIdx.x == 0) {
        double mean = sh[0] / N;
        double var  = sh2[0] / N - mean * mean;
        if (var < 0.0) var = 0.0;
        mu[c] = mean;
        Ad[c] = (g ? (double)g[c] : 1.0) / sqrt(var + 1e-5);
        Bd[c] = b ? (double)b[c] : 0.0;
    }
}

__global__ void k4_out(const int* __restrict__ v, const double* __restrict__ mu,
                       const double* __restrict__ Ad, float* __restrict__ out, int N) {
    int n = blockIdx.x * 256 + threadIdx.x;
    if (n >= N) return;
    double z[10];
    double mx = -1e300;
    for (int o = 0; o < 10; ++o) {
        z[o] = ((double)v[n * 10 + o] - mu[o]) * Ad[o];
        if (z[o] > mx) mx = z[o];
    }
    double s = 0.0;
    for (int o = 0; o < 10; ++o) s += exp(z[o] - mx);
    double l = mx + log(s);
    for (int o = 0; o < 10; ++o) out[n * 10 + o] = (float)(z[o] - l);
}

// ---------------- host ----------------
extern "C" void kernel_launch(void* const* d_in, const int* in_sizes, int n_in,
                              void* d_out, int out_size, void* d_ws, size_t ws_size,
                              hipStream_t stream) {
    const int N = in_sizes[0] / (3 * 32 * 32);   // 512

    const float* x   = (const float*)d_in[0];
    const float* w1  = (const float*)d_in[1];
    const float* g1  = (const float*)d_in[2];
    const float* b1  = (const float*)d_in[3];
    const float* w2  = (const float*)d_in[4];
    const float* g2  = (const float*)d_in[5];
    const float* b2  = (const float*)d_in[6];
    const float* w3  = (const float*)d_in[7];
    const float* g3  = (const float*)d_in[8];
    const float* b3  = (const float*)d_in[9];
    const float* w4  = (const float*)d_in[10];
    const float* g4  = (const float*)d_in[11];
    const float* b4  = (const float*)d_in[12];
    const float* w5  = (const float*)d_in[13];
    const float* g5  = (const float*)d_in[14];
    const float* b5  = (const float*)d_in[15];
    const float* w6  = (const float*)d_in[16];
    const float* g6  = (const float*)d_in[17];
    const float* b6  = (const float*)d_in[18];
    const float* wf1 = (const float*)d_in[19];
    const float* gf1 = (const float*)d_in[20];
    const float* bf1 = (const float*)d_in[21];
    const float* wf2 = (const float*)d_in[22];
    const float* gf2 = (const float*)d_in[23];
    const float* bf2 = (const float*)d_in[24];
    const float* wf3 = (const float*)d_in[25];

    char* ws = (char*)d_ws;
    size_t off = 0;
    auto alloc = [&](size_t bytes) -> char* {
        char* p = ws + off;
        off = (off + bytes + 511) & ~(size_t)511;
        return p;
    };

    // ---- DOWN region: all post-L1 buffers at distinct offsets ----
    int16_t* t2  = (int16_t*)alloc((size_t)N * 64 * 256 * 2);
    u64* p2B = (u64*)alloc((size_t)N * 256 * 8);
    u64* p2Z = (u64*)alloc((size_t)N * 256 * 8);
    int16_t* t3  = (int16_t*)alloc((size_t)N * 128 * 256 * 2);
    u64* p3B = (u64*)alloc((size_t)N * 256 * 2 * 8);
    u64* p3Z = (u64*)alloc((size_t)N * 256 * 2 * 8);
    int16_t* t4  = (int16_t*)alloc((size_t)N * 128 * 64 * 2);
    u64* p4B = (u64*)alloc((size_t)N * 64 * 2 * 8);
    u64* p4Z = (u64*)alloc((size_t)N * 64 * 2 * 8);
    int16_t* t5  = (int16_t*)alloc((size_t)N * 256 * 64 * 2);
    u64* p5B = (u64*)alloc((size_t)N * 64 * 4 * 8);
    u64* p5Z = (u64*)alloc((size_t)N * 64 * 4 * 8);
    int16_t* t6  = (int16_t*)alloc((size_t)N * 256 * 16 * 2);
    u64* p6B = (u64*)alloc((size_t)N * 64 * 8);
    u64* p6Z = (u64*)alloc((size_t)N * 64 * 8);
    int* fc1 = (int*)alloc((size_t)N * 512 * 4);
    int* fc2 = (int*)alloc((size_t)N * 512 * 4);
    int* fc3 = (int*)alloc((size_t)N * 10 * 4);
    u64* pF1B = (u64*)alloc((size_t)N * 8 * 8);
    u64* pF1Z = (u64*)alloc((size_t)N * 8 * 8);
    u64* pF2B = (u64*)alloc((size_t)N * 8 * 8);
    u64* pF2Z = (u64*)alloc((size_t)N * 8 * 8);
    size_t down_end = off;

    // ---- L1 head overlays (dead before any DOWN buffer is written) ----
    size_t head_big = (size_t)N * 64 * 1024 * 4;      // 134.2MB f32, 64 channels
    bool big = ws_size >= head_big + ((size_t)20 << 20);
    float*  c1buf = (float*)ws;                        // big: [N][64][1024]
    float*  c1buf8 = (float*)ws;                       // fallback: [N][8][1024]
    int8_t* sgnA  = (int8_t*)(ws + (size_t)N * 8 * 1024 * 4);  // fallback only

    // ---- tail (coexists with L1 head) ----
    off = big ? (head_big > down_end ? head_big : down_end) : down_end;
    off = (off + 511) & ~(size_t)511;
    u64* p1B = (u64*)alloc((size_t)N * 1024 * 8);
    u64* p1Z = (u64*)alloc((size_t)N * 1024 * 8);
    u64* wb2B = (u64*)alloc(64  * 9 * 1 * 8);  u64* wb2Z = (u64*)alloc(64  * 9 * 1 * 8);
    u64* wb3B = (u64*)alloc(128 * 9 * 1 * 8);  u64* wb3Z = (u64*)alloc(128 * 9 * 1 * 8);
    u64* wb4B = (u64*)alloc(128 * 9 * 2 * 8);  u64* wb4Z = (u64*)alloc(128 * 9 * 2 * 8);
    u64* wb5B = (u64*)alloc(256 * 9 * 2 * 8);  u64* wb5Z = (u64*)alloc(256 * 9 * 2 * 8);
    u64* wb6B = (u64*)alloc(256 * 9 * 4 * 8);  u64* wb6Z = (u64*)alloc(256 * 9 * 4 * 8);
    u64* wf1B = (u64*)alloc(512 * 64 * 8);     u64* wf1Z = (u64*)alloc(512 * 64 * 8);
    u64* wf2B = (u64*)alloc(512 * 8 * 8);      u64* wf2Z = (u64*)alloc(512 * 8 * 8);
    u64* wf3B = (u64*)alloc(10 * 8 * 8);       u64* wf3Z = (u64*)alloc(10 * 8 * 8);
    float* wt = (float*)alloc(27 * 64 * 4);
    double* Sp  = (double*)alloc(64 * 256 * 8);
    double* S2p = (double*)alloc(64 * 256 * 8);
    long long* SpI  = (long long*)alloc(256 * 32 * 8);
    long long* S2pI = (long long*)alloc(256 * 32 * 8);
    u64* flags = (u64*)alloc(16 * 8);
    // [0..4]=wconv L2..L6, [5..7]=wlin FC1..FC3, [8..12]=act L1..L5,
    // [13]=act flat(L6), [14]=act FC1sign, [15]=act FC2sign
    double* mu = (double*)alloc(512 * 8);
    double* Ad = (double*)alloc(512 * 8);
    double* Bd = (double*)alloc(512 * 8);
    float*  muF = (float*)alloc(64 * 4);
    float*  rF  = (float*)alloc(64 * 4);

    auto cdiv = [](int a, int b) { return (a + b - 1) / b; };

    // ---- flags + fused weight pack (incl. w1 ternary) ----
    kflag_init<<<1, 64, 0, stream>>>(flags);
    kpack_all<<<223, 256, 0, stream>>>(w1, w2, w3, w4, w5, w6, wf1, wf2, wf3, wt,
                                       wb2B, wb2Z, wb3B, wb3Z, wb4B, wb4Z,
                                       wb5B, wb5Z, wb6B, wb6Z, wf1B, wf1Z,
                                       wf2B, wf2Z, wf3B, wf3Z, flags);

    // ---- L1 ----
    if (big) {
        k1_conv_allv<<<(N * 256) / 256, 256, 0, stream>>>(x, wt, c1buf);
        k1_statsA<<<dim3(64, 4), 64, 0, stream>>>(c1buf, Sp, S2p, N);
        k1_statsB<<<64, 256, 0, stream>>>(Sp, S2p, muF, rF, N);
        k1_signpack<<<(N * 256) / 64, 64, 0, stream>>>(c1buf, muF, rF, g1, b1, p1B, p1Z, &flags[8]);
    } else {
        for (int grp = 0; grp < 8; ++grp) {
            k1_conv<<<dim3(16, 8, N), 64, 0, stream>>>(x, w1, c1buf8, grp);
            k1_stats<<<8, 256, 0, stream>>>(c1buf8, muF, rF, grp, N);
            k1_sign<<<dim3(4, 8, N), 256, 0, stream>>>(c1buf8, muF, rF, g1, b1, sgnA, grp);
        }
        kpack_sgn8<<<dim3(16, 1, N), 64, 0, stream>>>(sgnA, p1B, p1Z, 64, 1024, &flags[8]);
    }

    // ---- L2: conv+pool (Ci=64, 32x32 -> 16x16) ----
    kbconv_pool2<1, 8><<<dim3(4, 8, N), 64, 0, stream>>>(p1B, p1Z, wb2B, wb2Z, t2, 64, 32, 32, &flags[0], &flags[8]);
    kaccum16<<<dim3(64, 32), 256, 0, stream>>>(t2, SpI, S2pI, 64, 256, N * 256);
    kfinal2<<<1, 64, 0, stream>>>(SpI, S2pI, 32, g2, b2, mu, Ad, Bd, 64, N * 256);
    ksp_conv<<<cdiv(N * 1 * 64, 64), 64, 0, stream>>>(t2, mu, Ad, Bd, p2B, p2Z, 64, 256, N, &flags[9]);

    // ---- L3: conv (Ci=64, 16x16) ----
    kbconv2<1, 8><<<dim3(4, 16, N), 64, 0, stream>>>(p2B, p2Z, wb3B, wb3Z, t3, 128, 16, 16, &flags[1], &flags[9]);
    kaccum16<<<dim3(128, 16), 256, 0, stream>>>(t3, SpI, S2pI, 128, 256, N * 256);
    kfinal2<<<2, 64, 0, stream>>>(SpI, S2pI, 16, g3, b3, mu, Ad, Bd, 128, N * 256);
    ksp_conv<<<cdiv(N * 2 * 64, 64), 64, 0, stream>>>(t3, mu, Ad, Bd, p3B, p3Z, 128, 256, N, &flags[10]);

    // ---- L4: conv+pool (Ci=128, 16x16 -> 8x8) ----
    kbconv_pool2<2, 8><<<dim3(1, 16, N), 64, 0, stream>>>(p3B, p3Z, wb4B, wb4Z, t4, 128, 16, 16, &flags[2], &flags[10]);
    kaccum16<<<dim3(128, 16), 256, 0, stream>>>(t4, SpI, S2pI, 128, 64, N * 64);
    kfinal2<<<2, 64, 0, stream>>>(SpI, S2pI, 16, g4, b4, mu, Ad, Bd, 128, N * 64);
    ksp_conv<<<cdiv(N * 2 * 16, 64), 64, 0, stream>>>(t4, mu, Ad, Bd, p4B, p4Z, 128, 64, N, &flags[11]);

    // ---- L5: conv (Ci=128, 8x8) ----
    kbconv2<2, 8><<<dim3(1, 32, N), 64, 0, stream>>>(p4B, p4Z, wb5B, wb5Z, t5, 256, 8, 8, &flags[3], &flags[11]);
    kaccum16<<<dim3(256, 8), 256, 0, stream>>>(t5, SpI, S2pI, 256, 64, N * 64);
    kfinal2<<<4, 64, 0, stream>>>(SpI, S2pI, 8, g5, b5, mu, Ad, Bd, 256, N * 64);
    ksp_conv<<<cdiv(N * 4 * 16, 64), 64, 0, stream>>>(t5, mu, Ad, Bd, p5B, p5Z, 256, 64, N, &flags[12]);

    // ---- L6: conv+pool (Ci=256, 8x8 -> 4x4), positions-in-lanes ----
    kbconv_pool2s<4, 8><<<dim3(1, 32, N), 64, 0, stream>>>(p5B, p5Z, wb6B, wb6Z, t6, 256, 8, 8, &flags[4], &flags[12]);
    kaccum16<<<dim3(256, 2), 256, 0, stream>>>(t6, SpI, S2pI, 256, 16, N * 16);
    kfinal2<<<4, 64, 0, stream>>>(SpI, S2pI, 2, g6, b6, mu, Ad, Bd, 256, N * 16);
    ksp_flat<<<N, 64, 0, stream>>>(t6, mu, Ad, Bd, p6B, p6Z, &flags[13]);

    // ---- FC1 ----
    kbfc<<<dim3(8, N), 64, 0, stream>>>(p6B, p6Z, wf1B, wf1Z, fc1, 64, 512, &flags[5], &flags[13]);
    k3_stats<<<512, 256, 0, stream>>>(fc1, N, 512, gf1, bf1, mu, Ad, Bd);
    ksp_fc<<<cdiv(N * 8, 64), 64, 0, stream>>>(fc1, mu, Ad, Bd, pF1B, pF1Z, 512, 8, N, &flags[14]);

    // ---- FC2 ----
    kbfc<<<dim3(8, N), 64, 0, stream>>>(pF1B, pF1Z, wf2B, wf2Z, fc2, 8, 512, &flags[6], &flags[14]);
    k3_stats<<<512, 256, 0, stream>>>(fc2, N, 512, gf2, bf2, mu, Ad, Bd);
    ksp_fc<<<cdiv(N * 8, 64), 64, 0, stream>>>(fc2, mu, Ad, Bd, pF2B, pF2Z, 512, 8, N, &flags[15]);

    // ---- FC3 + bn(no affine) + log_softmax ----
    kbfc<<<dim3(1, N), 64, 0, stream>>>(pF2B, pF2Z, wf3B, wf3Z, fc3, 8, 10, &flags[7], &flags[15]);
    k3_stats<<<10, 256, 0, stream>>>(fc3, N, 10, nullptr, nullptr, mu, Ad, Bd);
    k4_out<<<cdiv(N, 256), 256, 0, stream>>>(fc3, mu, Ad, (float*)d_out, N);
}